// Round 9
// baseline (229.704 us; speedup 1.0000x reference)
//
#include <hip/hip_runtime.h>

// Capsule EM routing. B=32, H=W=8, I=32 -> N=2048, O=64, P=16, routings=3.
//
// R9: DIAGNOSTIC ROUND. Four falsified theories (occupancy R1/R5, launch
// ramp R5, DS-pipe pose reads R7, L1 line-scatter R8): 65536 wave-iters/pass
// always cost ~42-50us (~430 cyc/wave-iter/CU) regardless of the resource
// removed. Per the skill's ablation discipline: real path = R7 exactly
// (best-known structure, wt-transpose reverted as null), plus two probe
// dispatches AFTER stats_final writing only to dead workspace:
//   probe<1> = non-FIRST body, softmax removed (d kept alive via asm)
//   probe<3> = non-FIRST body, 1 i-iter instead of 8 (fixed-cost probe)
// Pre-committed decision table is in the session journal.

#define NB 32
#define NN 2048
#define NO 64
#define NP 16
#define EPSF 1e-7f

#define SPB 4                 // sites per block (one per 4-wave group)
#define NCHUNK 16             // chunks per batch sample
#define BLK_N (SPB * 32)      // 128 n per block

#define ACC_SLOTS 33
#define ACC_PER_B (ACC_SLOTS * NO)              // 2112 floats
#define PART_PER_BATCH (NCHUNK * ACC_PER_B)     // 33792 floats
#define PART_TOTAL (NB * PART_PER_BATCH)        // 1,081,344 floats

// non-atomic cross-wave reduce (barrier-sequenced) + coalesced partial store
__device__ __forceinline__ void reduce_store(
    float buf[SPB][ACC_PER_B], int wvin, int grp, int o, int tid,
    float accR, const float* acc1, const float* acc2, float* __restrict__ pc)
{
    if (wvin == 3) {
        float* r = buf[grp];
        r[32 * 64 + o] = accR;
        #pragma unroll
        for (int p = 0; p < 16; p++) r[p * 64 + o] = acc1[p];
        #pragma unroll
        for (int p = 0; p < 16; p++) r[(16 + p) * 64 + o] = acc2[p];
    }
    __syncthreads();
    for (int round = 2; round >= 0; --round) {
        if (wvin == round) {
            float* r = buf[grp];
            r[32 * 64 + o] += accR;
            #pragma unroll
            for (int p = 0; p < 16; p++) r[p * 64 + o] += acc1[p];
            #pragma unroll
            for (int p = 0; p < 16; p++) r[(16 + p) * 64 + o] += acc2[p];
        }
        __syncthreads();
    }
    for (int j = tid; j < ACC_PER_B; j += 1024)
        pc[j] = buf[0][j] + buf[1][j] + buf[2][j] + buf[3][j];
}

// shared stats prologue: sum partials of batch b into sb, compute per-o
// stats in place (mean / 0.5/var / zz_base)
__device__ __forceinline__ void stats_prologue(
    const float* __restrict__ part_prev, const float* __restrict__ beta_v,
    const float* __restrict__ beta_a, float inv_temp, int b, int tid, int o,
    float* sb)
{
    {
        const float4* p4 = (const float4*)(part_prev + (size_t)b * PART_PER_BATCH);
        float4* a4 = (float4*)sb;
        for (int j = tid; j < ACC_PER_B / 4; j += 1024) {
            float4 s = make_float4(0.f, 0.f, 0.f, 0.f);
            #pragma unroll
            for (int c = 0; c < NCHUNK; c++) {
                float4 vv = p4[c * (ACC_PER_B / 4) + j];
                s.x += vv.x; s.y += vv.y; s.z += vv.z; s.w += vv.w;
            }
            a4[j] = s;
        }
    }
    __syncthreads();
    if (tid < 64) {
        float rps = sb[32 * 64 + o];
        float mm[16], var[16];
        float logsum = 0.f;
        #pragma unroll
        for (int p = 0; p < 16; p++) {
            float s1 = sb[p * 64 + o];
            float s2 = sb[(16 + p) * 64 + o];
            float mv = s1 / rps;
            float vv = fmaxf(s2 / rps - mv * mv, 0.f);
            mm[p] = mv;
            var[p] = vv;
            logsum += __logf(sqrtf(vv) + EPSF);
        }
        float cost = rps * (16.0f * beta_v[o] + logsum);
        float cm = cost;
        #pragma unroll
        for (int s = 32; s > 0; s >>= 1) cm += __shfl_xor(cm, s, 64);
        cm *= (1.0f / 64.0f);
        float dd = cost - cm;
        float cs = dd * dd;
        #pragma unroll
        for (int s = 32; s > 0; s >>= 1) cs += __shfl_xor(cs, s, 64);
        cs = sqrtf(cs * (1.0f / 64.0f));
        float x = inv_temp * (beta_a[o] + (cm - cost) / (cs + EPSF));
        float oa = 1.0f / (1.0f + __expf(-x));
        #pragma unroll
        for (int p = 0; p < 16; p++) sb[p * 64 + o] = mm[p];
        #pragma unroll
        for (int p = 0; p < 16; p++) sb[(16 + p) * 64 + o] = 0.5f / var[p];
        sb[32 * 64 + o] = __logf(oa + EPSF) - logsum;
    }
    __syncthreads();
}

template <bool FIRST>
__global__ __launch_bounds__(1024) void accum_kernel(
    const float* __restrict__ pose,      // [B][N][16]
    const float* __restrict__ act,       // [B][N]
    const float* __restrict__ wmat,      // [I=32][O=64][16]
    const float* __restrict__ beta_v,    // [64]
    const float* __restrict__ beta_a,    // [64]
    const float* __restrict__ part_prev, // [B][16][33*64] or null (FIRST)
    float* __restrict__ part_out,        // [B][16][33*64]
    float inv_temp)
{
    __shared__ float buf[SPB][ACC_PER_B];    // 33.8 KB

    const int b = blockIdx.y;
    const int chunk = blockIdx.x;
    const int n0 = chunk * BLK_N;
    const int tid = threadIdx.x;
    const int wv = tid >> 6, grp = wv >> 2, wvin = wv & 3, o = tid & 63;

    float m[16], i2v[16], zzb = 0.f;
    if (!FIRST) {
        float* sb = buf[0];
        stats_prologue(part_prev, beta_v, beta_a, inv_temp, b, tid, o, sb);
        #pragma unroll
        for (int p = 0; p < 16; p++) m[p] = sb[p * 64 + o];
        #pragma unroll
        for (int p = 0; p < 16; p++) i2v[p] = sb[(16 + p) * 64 + o];
        zzb = sb[32 * 64 + o];
        __syncthreads();
    }

    const float* pose_b = pose + ((size_t)b * NN + n0) * 16;
    const float* act_b  = act + (size_t)b * NN + n0;
    const int site = chunk * SPB + grp;
    const float c0 = ((site >> 3) + 0.5f) * 0.125f;
    const float c1 = ((site & 7) + 0.5f) * 0.125f;

    float accR = 0.f, acc1[16], acc2[16];
    #pragma unroll
    for (int p = 0; p < 16; p++) { acc1[p] = 0.f; acc2[p] = 0.f; }

    for (int ii = 0; ii < 8; ii++) {
        const int i = wvin * 8 + ii;
        const int nl = __builtin_amdgcn_readfirstlane(grp * 32 + i);
        const float4* pr4 = (const float4*)(pose_b + (size_t)nl * 16);
        const float av = act_b[nl];

        const float4* wp = (const float4*)(wmat + ((size_t)i * 64 + o) * 16);
        float4 w0 = wp[0], w1 = wp[1], w2 = wp[2], w3 = wp[3];

        float v[16];
        #pragma unroll
        for (int a = 0; a < 4; a++) {
            float4 pa = pr4[a];
            v[a * 4 + 0] = pa.x * w0.x + pa.y * w1.x + pa.z * w2.x + pa.w * w3.x;
            v[a * 4 + 1] = pa.x * w0.y + pa.y * w1.y + pa.z * w2.y + pa.w * w3.y;
            v[a * 4 + 2] = pa.x * w0.z + pa.y * w1.z + pa.z * w2.z + pa.w * w3.z;
            v[a * 4 + 3] = pa.x * w0.w + pa.y * w1.w + pa.z * w2.w + pa.w * w3.w;
        }
        v[0] += c0;
        v[1] += c1;

        float rr;
        if (FIRST) {
            rr = 1.0f / 64.0f;
        } else {
            float d = zzb;
            #pragma unroll
            for (int p = 0; p < 16; p++) {
                float t = v[p] - m[p];
                d -= t * t * i2v[p];
            }
            float mx = d;
            #pragma unroll
            for (int s = 32; s > 0; s >>= 1) mx = fmaxf(mx, __shfl_xor(mx, s, 64));
            float e = __expf(d - mx);
            float sum = e;
            #pragma unroll
            for (int s = 32; s > 0; s >>= 1) sum += __shfl_xor(sum, s, 64);
            rr = e / sum;
        }
        float rp = rr * av;
        accR += rp;
        #pragma unroll
        for (int p = 0; p < 16; p++) {
            acc1[p] += rp * v[p];
            acc2[p] += rp * v[p] * v[p];
        }
    }

    float* pc = part_out + ((size_t)b * NCHUNK + chunk) * ACC_PER_B;
    reduce_store(buf, wvin, grp, o, tid, accR, acc1, acc2, pc);
}

// ---- diagnostic probes (write only to dead workspace, launched last) ----
// VAR==1: softmax removed (d kept alive), 8 iters.  VAR==3: 1 iter, full
// softmax.  Everything else identical to accum_kernel<false>.
template <int VAR>
__global__ __launch_bounds__(1024) void probe_kernel(
    const float* __restrict__ pose, const float* __restrict__ act,
    const float* __restrict__ wmat, const float* __restrict__ beta_v,
    const float* __restrict__ beta_a, const float* __restrict__ part_prev,
    float* __restrict__ part_out, float inv_temp)
{
    __shared__ float buf[SPB][ACC_PER_B];

    const int b = blockIdx.y;
    const int chunk = blockIdx.x;
    const int n0 = chunk * BLK_N;
    const int tid = threadIdx.x;
    const int wv = tid >> 6, grp = wv >> 2, wvin = wv & 3, o = tid & 63;

    float m[16], i2v[16], zzb = 0.f;
    {
        float* sb = buf[0];
        stats_prologue(part_prev, beta_v, beta_a, inv_temp, b, tid, o, sb);
        #pragma unroll
        for (int p = 0; p < 16; p++) m[p] = sb[p * 64 + o];
        #pragma unroll
        for (int p = 0; p < 16; p++) i2v[p] = sb[(16 + p) * 64 + o];
        zzb = sb[32 * 64 + o];
        __syncthreads();
    }

    const float* pose_b = pose + ((size_t)b * NN + n0) * 16;
    const float* act_b  = act + (size_t)b * NN + n0;
    const int site = chunk * SPB + grp;
    const float c0 = ((site >> 3) + 0.5f) * 0.125f;
    const float c1 = ((site & 7) + 0.5f) * 0.125f;

    float accR = 0.f, acc1[16], acc2[16];
    #pragma unroll
    for (int p = 0; p < 16; p++) { acc1[p] = 0.f; acc2[p] = 0.f; }

    const int iters = (VAR == 3) ? 1 : 8;
    for (int ii = 0; ii < iters; ii++) {
        const int i = wvin * 8 + ii;
        const int nl = __builtin_amdgcn_readfirstlane(grp * 32 + i);
        const float4* pr4 = (const float4*)(pose_b + (size_t)nl * 16);
        const float av = act_b[nl];

        const float4* wp = (const float4*)(wmat + ((size_t)i * 64 + o) * 16);
        float4 w0 = wp[0], w1 = wp[1], w2 = wp[2], w3 = wp[3];

        float v[16];
        #pragma unroll
        for (int a = 0; a < 4; a++) {
            float4 pa = pr4[a];
            v[a * 4 + 0] = pa.x * w0.x + pa.y * w1.x + pa.z * w2.x + pa.w * w3.x;
            v[a * 4 + 1] = pa.x * w0.y + pa.y * w1.y + pa.z * w2.y + pa.w * w3.y;
            v[a * 4 + 2] = pa.x * w0.z + pa.y * w1.z + pa.z * w2.z + pa.w * w3.z;
            v[a * 4 + 3] = pa.x * w0.w + pa.y * w1.w + pa.z * w2.w + pa.w * w3.w;
        }
        v[0] += c0;
        v[1] += c1;

        float d = zzb;
        #pragma unroll
        for (int p = 0; p < 16; p++) {
            float t = v[p] - m[p];
            d -= t * t * i2v[p];
        }

        float rr;
        if (VAR == 1) {
            // softmax ablated; keep d (and its whole upstream chain) alive
            asm volatile("" :: "v"(d));
            rr = 1.0f / 64.0f;
        } else {
            float mx = d;
            #pragma unroll
            for (int s = 32; s > 0; s >>= 1) mx = fmaxf(mx, __shfl_xor(mx, s, 64));
            float e = __expf(d - mx);
            float sum = e;
            #pragma unroll
            for (int s = 32; s > 0; s >>= 1) sum += __shfl_xor(sum, s, 64);
            rr = e / sum;
        }
        float rp = rr * av;
        accR += rp;
        #pragma unroll
        for (int p = 0; p < 16; p++) {
            acc1[p] += rp * v[p];
            acc2[p] += rp * v[p] * v[p];
        }
    }

    float* pc = part_out + ((size_t)b * NCHUNK + chunk) * ACC_PER_B;
    reduce_store(buf, wvin, grp, o, tid, accR, acc1, acc2, pc);
}

__global__ __launch_bounds__(256) void stats_final(
    const float* __restrict__ part, const float* __restrict__ beta_v,
    const float* __restrict__ beta_a, float* __restrict__ out, float inv_temp)
{
    __shared__ float acc_s[ACC_PER_B];

    const int b = blockIdx.x;
    const int tid = threadIdx.x;

    {
        const float4* p4 = (const float4*)(part + (size_t)b * PART_PER_BATCH);
        float4* a4 = (float4*)acc_s;
        for (int j = tid; j < ACC_PER_B / 4; j += 256) {
            float4 s = make_float4(0.f, 0.f, 0.f, 0.f);
            #pragma unroll
            for (int c = 0; c < NCHUNK; c++) {
                float4 vv = p4[c * (ACC_PER_B / 4) + j];
                s.x += vv.x; s.y += vv.y; s.z += vv.z; s.w += vv.w;
            }
            a4[j] = s;
        }
    }
    __syncthreads();

    if (tid < 64) {
        const int o = tid;
        float rps = acc_s[32 * 64 + o];
        float m[16];
        float logsum = 0.f;
        #pragma unroll
        for (int p = 0; p < 16; p++) {
            float s1 = acc_s[p * 64 + o];
            float s2 = acc_s[(16 + p) * 64 + o];
            float mm = s1 / rps;
            float vv = fmaxf(s2 / rps - mm * mm, 0.f);
            m[p] = mm;
            logsum += __logf(sqrtf(vv) + EPSF);
        }
        float cost = rps * (16.0f * beta_v[o] + logsum);

        float cm = cost;
        #pragma unroll
        for (int s = 32; s > 0; s >>= 1) cm += __shfl_xor(cm, s, 64);
        cm *= (1.0f / 64.0f);
        float dd = cost - cm;
        float cs = dd * dd;
        #pragma unroll
        for (int s = 32; s > 0; s >>= 1) cs += __shfl_xor(cs, s, 64);
        cs = sqrtf(cs * (1.0f / 64.0f));

        float x = inv_temp * (beta_a[o] + (cm - cost) / (cs + EPSF));
        float oa = 1.0f / (1.0f + __expf(-x));

        float* op = out + ((size_t)b * 64 + o) * 16;
        #pragma unroll
        for (int p = 0; p < 16; p++) op[p] = m[p];
        out[(size_t)NB * NO * NP + (size_t)b * 64 + o] = oa;
    }
}

extern "C" void kernel_launch(void* const* d_in, const int* in_sizes, int n_in,
                              void* d_out, int out_size, void* d_ws, size_t ws_size,
                              hipStream_t stream) {
    const float* pose   = (const float*)d_in[0];
    const float* act    = (const float*)d_in[1];
    const float* wmat   = (const float*)d_in[2];
    const float* beta_v = (const float*)d_in[3];
    const float* beta_a = (const float*)d_in[4];
    float* out = (float*)d_out;
    float* ws = (float*)d_ws;

    float* pA = ws;                        // 1,081,344 floats
    float* pB = ws + (size_t)PART_TOTAL;   // 1,081,344 floats

    dim3 grid(NCHUNK, NB);
    accum_kernel<true ><<<grid, 1024, 0, stream>>>(pose, act, wmat, beta_v, beta_a,
                                                   nullptr, pA, 0.0f);
    accum_kernel<false><<<grid, 1024, 0, stream>>>(pose, act, wmat, beta_v, beta_a,
                                                   pA, pB, 1.0f);
    accum_kernel<false><<<grid, 1024, 0, stream>>>(pose, act, wmat, beta_v, beta_a,
                                                   pB, pA, 2.0f);
    stats_final<<<NB, 256, 0, stream>>>(pA, beta_v, beta_a, out, 3.0f);

    // diagnostics: read pA (final partials, valid floats), write pB (dead)
    probe_kernel<1><<<grid, 1024, 0, stream>>>(pose, act, wmat, beta_v, beta_a,
                                               pA, pB, 2.0f);
    probe_kernel<3><<<grid, 1024, 0, stream>>>(pose, act, wmat, beta_v, beta_a,
                                               pA, pB, 2.0f);
}

// Round 11
// 173.125 us; speedup vs baseline: 1.3268x; 1.3268x over previous
//
#include <hip/hip_runtime.h>

// Capsule EM routing. B=32, H=W=8, I=32 -> N=2048, O=64, P=16, routings=3.
//
// R11: consolidate on the measured-best pieces; no structural bets.
// Grid-sync axis is DEAD (R6 cooperative API poisons graph capture; R10
// spin barrier hung). Best measured accum shape is R1's: 2048 blocks x 256
// thd (block = 1 site, wave = 8 i-iters, LDS pose staging, 4-wave tree
// reduce, global fp32 atomicAdd into [B][33][64]) at 41.8us -- faster than
// every 16-wave variant (46us: 16-wave __syncthreads costs, no gain).
// Changes vs R1 (both additive, both on proven mechanisms):
//  1. stats fused into the following accum (R7-proven): each wave
//     redundantly computes the per-o stats from the atomically-summed
//     accum_prev (0.27MB) -- no barriers added, since every wave holds all
//     64 o-lanes. 6 dispatches -> 4.
//  2. Mahalanobis algebra: d = zzc + sum_p v*(Bp - v*i2v), with
//     Bp = 2*m*i2v, zzc = zzb - sum m^2*i2v hoisted out of the i-loop.
//     -16 VALU/iter; register-neutral (Bp replaces m). Plus __fdividef.
// R9 facts: fixed ~= 12us/dispatch, softmax+prologue hidden; R4 lesson: no
// unroll pragmas; R3 lesson: no launch_bounds second-arg games.

#define NB 32
#define NN 2048
#define NO 64
#define NP 16
#define EPSF 1e-7f

#define CHUNKS 64          // blocks per batch = spatial sites
#define CHN 32             // n per block = 1 site

// accum layout per pass: [b][slot][o], slots 0..15 = sum rr'*v,
// 16..31 = sum rr'*v^2, 32 = rps
#define ACC_SLOTS 33
#define ACC_PER_B (ACC_SLOTS * NO)   // 2112 floats
#define ACC_TOTAL (NB * ACC_PER_B)   // 67584 floats

template <bool FIRST>
__global__ __launch_bounds__(256) void accum_kernel(
    const float* __restrict__ pose,        // [B][N][16]
    const float* __restrict__ act,         // [B][N]
    const float* __restrict__ wmat,        // [32][64][16]
    const float* __restrict__ beta_v,      // [64]
    const float* __restrict__ beta_a,      // [64]
    const float* __restrict__ accum_prev,  // [B][33][64] summed, or null
    float* __restrict__ accum_out,         // [B][33][64] pre-zeroed
    float inv_temp)                        // temperature of the PREV iter
{
    __shared__ float pose_s[CHN * 16];     // 2 KB (one site: 32 poses)
    __shared__ float act_s[CHN];
    __shared__ float red[2][ACC_PER_B];    // 16.9 KB tree-reduce buffer

    const int b = blockIdx.y;
    const int site = blockIdx.x;           // 0..63
    const int n0 = site * CHN;
    const int tid = threadIdx.x;

    // cooperative load of this site's poses + activations
    {
        const float4* psrc = (const float4*)(pose + ((size_t)b * NN + n0) * 16);
        float4* pdst = (float4*)pose_s;
        if (tid < CHN * 4) pdst[tid] = psrc[tid];   // 128 float4s
        if (tid < CHN) act_s[tid] = act[(size_t)b * NN + n0 + tid];
    }
    __syncthreads();

    const int wv = tid >> 6;    // wave 0..3 -> i-range [wv*8, wv*8+8)
    const int o = tid & 63;     // lane = output capsule

    // ---- fused stats of the previous pass (redundant per wave; no sync:
    //      each wave holds all 64 o-lanes, shuffles stay wave-local) ----
    float i2v[16], Bp[16], zzc = 0.f;
    if (!FIRST) {
        const float* ap = accum_prev + (size_t)b * ACC_PER_B;
        float rps = ap[32 * 64 + o];
        float rinv = 1.0f / rps;
        float logsum = 0.f, msum = 0.f;
        #pragma unroll
        for (int p = 0; p < 16; p++) {
            float mm = ap[p * 64 + o] * rinv;
            float vv = fmaxf(ap[(16 + p) * 64 + o] * rinv - mm * mm, 0.f);
            float iv = 0.5f / vv;
            i2v[p] = iv;
            Bp[p] = 2.0f * mm * iv;
            msum = fmaf(mm * mm, iv, msum);
            logsum += __logf(sqrtf(vv) + EPSF);
        }
        float cost = rps * (16.0f * beta_v[o] + logsum);
        float cm = cost;
        #pragma unroll
        for (int s = 32; s > 0; s >>= 1) cm += __shfl_xor(cm, s, 64);
        cm *= (1.0f / 64.0f);
        float dd = cost - cm;
        float cs = dd * dd;
        #pragma unroll
        for (int s = 32; s > 0; s >>= 1) cs += __shfl_xor(cs, s, 64);
        cs = sqrtf(cs * (1.0f / 64.0f));
        float x = inv_temp * (beta_a[o] + (cm - cost) / (cs + EPSF));
        float oa = 1.0f / (1.0f + __expf(-x));
        // zzc = log(oa+eps) - sum log(sigma+eps) - sum m^2*i2v
        zzc = __logf(oa + EPSF) - logsum - msum;
    }

    // ---- accumulation over this wave's 8 input capsules ----
    const float c0 = ((site >> 3) + 0.5f) * 0.125f;
    const float c1 = ((site & 7) + 0.5f) * 0.125f;

    float accR = 0.f, acc1[16], acc2[16];
    #pragma unroll
    for (int p = 0; p < 16; p++) { acc1[p] = 0.f; acc2[p] = 0.f; }

    for (int ii = 0; ii < 8; ii++) {
        const int i = wv * 8 + ii;           // capsule = local n (0..31)
        const float4* wp = (const float4*)(wmat + ((size_t)i * 64 + o) * 16);
        float4 w0 = wp[0], w1 = wp[1], w2 = wp[2], w3 = wp[3];  // rows k
        const float* pr = pose_s + i * 16;   // broadcast reads
        float v[16];
        #pragma unroll
        for (int a = 0; a < 4; a++) {
            float pa0 = pr[a * 4 + 0], pa1 = pr[a * 4 + 1];
            float pa2 = pr[a * 4 + 2], pa3 = pr[a * 4 + 3];
            v[a * 4 + 0] = pa0 * w0.x + pa1 * w1.x + pa2 * w2.x + pa3 * w3.x;
            v[a * 4 + 1] = pa0 * w0.y + pa1 * w1.y + pa2 * w2.y + pa3 * w3.y;
            v[a * 4 + 2] = pa0 * w0.z + pa1 * w1.z + pa2 * w2.z + pa3 * w3.z;
            v[a * 4 + 3] = pa0 * w0.w + pa1 * w1.w + pa2 * w2.w + pa3 * w3.w;
        }
        v[0] += c0;
        v[1] += c1;

        float rr;
        if (FIRST) {
            rr = 1.0f / 64.0f;
        } else {
            // d = zzb - sum (v-m)^2*i2v  ==  zzc + sum v*(Bp - v*i2v)
            float d = zzc;
            #pragma unroll
            for (int p = 0; p < 16; p++) {
                float inner = fmaf(-v[p], i2v[p], Bp[p]);
                d = fmaf(v[p], inner, d);
            }
            // softmax over the 64 o-lanes
            float mx = d;
            #pragma unroll
            for (int s = 32; s > 0; s >>= 1) mx = fmaxf(mx, __shfl_xor(mx, s, 64));
            float e = __expf(d - mx);
            float sum = e;
            #pragma unroll
            for (int s = 32; s > 0; s >>= 1) sum += __shfl_xor(sum, s, 64);
            rr = __fdividef(e, sum);
        }
        float rp = rr * act_s[i];
        accR += rp;
        #pragma unroll
        for (int p = 0; p < 16; p++) {
            acc1[p] += rp * v[p];
            acc2[p] += rp * v[p] * v[p];
        }
    }

    // ---- non-atomic 4-wave LDS tree reduce (R1-proven), then atomics ----
    if (wv >= 2) {
        float* r = red[wv - 2];
        r[32 * 64 + o] = accR;
        #pragma unroll
        for (int p = 0; p < 16; p++) r[p * 64 + o] = acc1[p];
        #pragma unroll
        for (int p = 0; p < 16; p++) r[(16 + p) * 64 + o] = acc2[p];
    }
    __syncthreads();
    if (wv < 2) {
        const float* r = red[wv];
        accR += r[32 * 64 + o];
        #pragma unroll
        for (int p = 0; p < 16; p++) acc1[p] += r[p * 64 + o];
        #pragma unroll
        for (int p = 0; p < 16; p++) acc2[p] += r[(16 + p) * 64 + o];
    }
    __syncthreads();
    if (wv == 1) {
        float* r = red[0];
        r[32 * 64 + o] = accR;
        #pragma unroll
        for (int p = 0; p < 16; p++) r[p * 64 + o] = acc1[p];
        #pragma unroll
        for (int p = 0; p < 16; p++) r[(16 + p) * 64 + o] = acc2[p];
    }
    __syncthreads();
    if (wv == 0) {
        const float* r = red[0];
        accR += r[32 * 64 + o];
        #pragma unroll
        for (int p = 0; p < 16; p++) acc1[p] += r[p * 64 + o];
        #pragma unroll
        for (int p = 0; p < 16; p++) acc2[p] += r[(16 + p) * 64 + o];

        float* ac = accum_out + (size_t)b * ACC_PER_B;
        atomicAdd(ac + 32 * 64 + o, accR);
        #pragma unroll
        for (int p = 0; p < 16; p++) atomicAdd(ac + p * 64 + o, acc1[p]);
        #pragma unroll
        for (int p = 0; p < 16; p++) atomicAdd(ac + (16 + p) * 64 + o, acc2[p]);
    }
}

__global__ __launch_bounds__(64) void stats_final(
    const float* __restrict__ accum,   // [B][33][64] summed
    const float* __restrict__ beta_v,  // [64]
    const float* __restrict__ beta_a,  // [64]
    float* __restrict__ out,
    float inv_temp)
{
    const int b = blockIdx.x;
    const int o = threadIdx.x;  // 64 threads = 1 wave
    const float* ac = accum + (size_t)b * ACC_PER_B;

    float rps = ac[32 * 64 + o];
    float rinv = 1.0f / rps;
    float m[16];
    float logsum = 0.f;
    #pragma unroll
    for (int p = 0; p < 16; p++) {
        float mm = ac[p * 64 + o] * rinv;
        float vv = fmaxf(ac[(16 + p) * 64 + o] * rinv - mm * mm, 0.f);
        m[p] = mm;
        logsum += __logf(sqrtf(vv) + EPSF);
    }
    float cost = rps * (16.0f * beta_v[o] + logsum);

    float cm = cost;
    #pragma unroll
    for (int s = 32; s > 0; s >>= 1) cm += __shfl_xor(cm, s, 64);
    cm *= (1.0f / 64.0f);
    float dd = cost - cm;
    float cs = dd * dd;
    #pragma unroll
    for (int s = 32; s > 0; s >>= 1) cs += __shfl_xor(cs, s, 64);
    cs = sqrtf(cs * (1.0f / 64.0f));

    float x = inv_temp * (beta_a[o] + (cm - cost) / (cs + EPSF));
    float oa = 1.0f / (1.0f + __expf(-x));

    float* op = out + ((size_t)b * 64 + o) * 16;
    #pragma unroll
    for (int p = 0; p < 16; p++) op[p] = m[p];
    out[(size_t)NB * NO * NP + (size_t)b * 64 + o] = oa;
}

extern "C" void kernel_launch(void* const* d_in, const int* in_sizes, int n_in,
                              void* d_out, int out_size, void* d_ws, size_t ws_size,
                              hipStream_t stream) {
    const float* pose   = (const float*)d_in[0];  // (32,8,8,32,4,4)
    const float* act    = (const float*)d_in[1];  // (32,8,8,32)
    const float* wmat   = (const float*)d_in[2];  // (32,64,4,4)
    const float* beta_v = (const float*)d_in[3];  // (1,64)
    const float* beta_a = (const float*)d_in[4];  // (1,64)
    float* out = (float*)d_out;
    float* ws = (float*)d_ws;

    float* a0 = ws;
    float* a1 = ws + (size_t)ACC_TOTAL;
    float* a2 = ws + 2 * (size_t)ACC_TOTAL;

    // zero the three atomic accumulators (ws is poisoned before every call)
    hipMemsetAsync(ws, 0, 3 * (size_t)ACC_TOTAL * sizeof(float), stream);

    dim3 grid(CHUNKS, NB);
    accum_kernel<true ><<<grid, 256, 0, stream>>>(pose, act, wmat, beta_v, beta_a,
                                                  nullptr, a0, 0.0f);
    accum_kernel<false><<<grid, 256, 0, stream>>>(pose, act, wmat, beta_v, beta_a,
                                                  a0, a1, 1.0f);
    accum_kernel<false><<<grid, 256, 0, stream>>>(pose, act, wmat, beta_v, beta_a,
                                                  a1, a2, 2.0f);
    stats_final<<<NB, 64, 0, stream>>>(a2, beta_v, beta_a, out, 3.0f);
}

// Round 12
// 165.069 us; speedup vs baseline: 1.3916x; 1.0488x over previous
//
#include <hip/hip_runtime.h>

// Capsule EM routing. B=32, H=W=8, I=32 -> N=2048, O=64, P=16, routings=3.
//
// R12: loop interchange -- w in registers. Accum is pinned at 42-50us
// across occupancy/block-shape/staging/coalescing/softmax variants; the one
// shared constant is wmat operand volume: every (site,i,o) reloads 64B of w
// => 268 MB/pass through L1/L2 (L1 thrashes: 128KB slice vs 32KB L1), and
// FETCH_SIZE can't see it (HBM-only counter). Since each EM row n=(site,i)
// is independent, fix i per wave and iterate sites: the wave's w-row (16
// floats) loads ONCE into VGPRs and serves 8 sites -> 33 MB/pass (8x less),
// and the inner loop has ZERO vector-memory instructions (pose/act via LDS
// broadcast, R1-proven). Block = 4 waves = 4 i x 8 sites; grid 2048x256
// (R1's measured-best shape). Fused stats prologue kept (saves 2 launches)
// but reverted to stable (v-m)^2 math (R11's expanded algebra doubled
// absmax). Tree reduce + global fp32 atomics exactly R1. No unroll pragmas
// (R4), no launch_bounds games (R3), no atomic LDS (R3), no grid sync
// (R6/R10).

#define NB 32
#define NN 2048
#define NO 64
#define NP 16
#define EPSF 1e-7f

// block tiling: 8 sites x 4 i per block; 64 blocks per batch
#define SITES_PB 8
#define IS_PB 4
#define PAIRS_PB (SITES_PB * IS_PB)   // 32 (site,i) pairs per block

#define ACC_SLOTS 33
#define ACC_PER_B (ACC_SLOTS * NO)    // 2112 floats
#define ACC_TOTAL (NB * ACC_PER_B)    // 67584 floats

template <bool FIRST>
__global__ __launch_bounds__(256) void accum_kernel(
    const float* __restrict__ pose,        // [B][N][16]
    const float* __restrict__ act,         // [B][N]
    const float* __restrict__ wmat,        // [32][64][16]
    const float* __restrict__ beta_v,      // [64]
    const float* __restrict__ beta_a,      // [64]
    const float* __restrict__ accum_prev,  // [B][33][64] summed, or null
    float* __restrict__ accum_out,         // [B][33][64] pre-zeroed
    float inv_temp)                        // temperature of the PREV iter
{
    __shared__ float pose_s[PAIRS_PB * 16];   // 2 KB
    __shared__ float act_s[PAIRS_PB];
    __shared__ float red[2][ACC_PER_B];       // 16.9 KB tree-reduce buffer

    const int b = blockIdx.y;
    const int sg = blockIdx.x >> 3;           // site-group 0..7
    const int ig = blockIdx.x & 7;            // i-group 0..7
    const int s0 = sg * SITES_PB;             // first site
    const int i0 = ig * IS_PB;                // first input capsule
    const int tid = threadIdx.x;
    const int wv = tid >> 6;                  // wave 0..3 -> i = i0+wv
    const int o = tid & 63;                   // lane = output capsule

    // ---- stage this block's 32 (site,i) poses + acts (64B chunks) ----
    {
        if (tid < PAIRS_PB * 4) {
            const int pair = tid >> 2, qw = tid & 3;
            const int sl = pair >> 2, li = pair & 3;
            const size_t n = (size_t)b * NN + (s0 + sl) * 32 + (i0 + li);
            ((float4*)pose_s)[pair * 4 + qw] =
                ((const float4*)(pose + n * 16))[qw];
        }
        if (tid < PAIRS_PB) {
            const int sl = tid >> 2, li = tid & 3;
            act_s[tid] = act[(size_t)b * NN + (s0 + sl) * 32 + (i0 + li)];
        }
    }

    // ---- wave-persistent w row: w[(i0+wv)][o][16] loaded ONCE ----
    const float4* wp = (const float4*)(wmat + (((size_t)(i0 + wv)) * 64 + o) * 16);
    float4 w0 = wp[0], w1 = wp[1], w2 = wp[2], w3 = wp[3];

    // ---- fused stats of the previous pass (per wave; wave-local shuffles) ----
    float m[16], i2v[16], zzb = 0.f;
    if (!FIRST) {
        const float* ap = accum_prev + (size_t)b * ACC_PER_B;
        float rps = ap[32 * 64 + o];
        float rinv = 1.0f / rps;
        float logsum = 0.f;
        #pragma unroll
        for (int p = 0; p < 16; p++) {
            float mm = ap[p * 64 + o] * rinv;
            float vv = fmaxf(ap[(16 + p) * 64 + o] * rinv - mm * mm, 0.f);
            m[p] = mm;
            i2v[p] = 0.5f / vv;
            logsum += __logf(sqrtf(vv) + EPSF);
        }
        float cost = rps * (16.0f * beta_v[o] + logsum);
        float cm = cost;
        #pragma unroll
        for (int s = 32; s > 0; s >>= 1) cm += __shfl_xor(cm, s, 64);
        cm *= (1.0f / 64.0f);
        float dd = cost - cm;
        float cs = dd * dd;
        #pragma unroll
        for (int s = 32; s > 0; s >>= 1) cs += __shfl_xor(cs, s, 64);
        cs = sqrtf(cs * (1.0f / 64.0f));
        float x = inv_temp * (beta_a[o] + (cm - cost) / (cs + EPSF));
        float oa = 1.0f / (1.0f + __expf(-x));
        zzb = __logf(oa + EPSF) - logsum;
    }
    __syncthreads();   // staging complete

    float accR = 0.f, acc1[16], acc2[16];
    #pragma unroll
    for (int p = 0; p < 16; p++) { acc1[p] = 0.f; acc2[p] = 0.f; }

    // ---- inner loop over the 8 sites: ZERO vector-memory instructions ----
    for (int sl = 0; sl < 8; sl++) {
        const int site = s0 + sl;
        const float c0 = ((site >> 3) + 0.5f) * 0.125f;
        const float c1 = ((site & 7) + 0.5f) * 0.125f;
        const float* pr = pose_s + (sl * 4 + wv) * 16;   // broadcast reads

        float v[16];
        #pragma unroll
        for (int a = 0; a < 4; a++) {
            float pa0 = pr[a * 4 + 0], pa1 = pr[a * 4 + 1];
            float pa2 = pr[a * 4 + 2], pa3 = pr[a * 4 + 3];
            v[a * 4 + 0] = pa0 * w0.x + pa1 * w1.x + pa2 * w2.x + pa3 * w3.x;
            v[a * 4 + 1] = pa0 * w0.y + pa1 * w1.y + pa2 * w2.y + pa3 * w3.y;
            v[a * 4 + 2] = pa0 * w0.z + pa1 * w1.z + pa2 * w2.z + pa3 * w3.z;
            v[a * 4 + 3] = pa0 * w0.w + pa1 * w1.w + pa2 * w2.w + pa3 * w3.w;
        }
        v[0] += c0;
        v[1] += c1;

        float rr;
        if (FIRST) {
            rr = 1.0f / 64.0f;
        } else {
            float d = zzb;
            #pragma unroll
            for (int p = 0; p < 16; p++) {
                float t = v[p] - m[p];
                d -= t * t * i2v[p];
            }
            // softmax over the 64 o-lanes
            float mx = d;
            #pragma unroll
            for (int s = 32; s > 0; s >>= 1) mx = fmaxf(mx, __shfl_xor(mx, s, 64));
            float e = __expf(d - mx);
            float sum = e;
            #pragma unroll
            for (int s = 32; s > 0; s >>= 1) sum += __shfl_xor(sum, s, 64);
            rr = e / sum;
        }
        float rp = rr * act_s[sl * 4 + wv];
        accR += rp;
        #pragma unroll
        for (int p = 0; p < 16; p++) {
            acc1[p] += rp * v[p];
            acc2[p] += rp * v[p] * v[p];
        }
    }

    // ---- non-atomic 4-wave LDS tree reduce (R1-proven), then atomics ----
    if (wv >= 2) {
        float* r = red[wv - 2];
        r[32 * 64 + o] = accR;
        #pragma unroll
        for (int p = 0; p < 16; p++) r[p * 64 + o] = acc1[p];
        #pragma unroll
        for (int p = 0; p < 16; p++) r[(16 + p) * 64 + o] = acc2[p];
    }
    __syncthreads();
    if (wv < 2) {
        const float* r = red[wv];
        accR += r[32 * 64 + o];
        #pragma unroll
        for (int p = 0; p < 16; p++) acc1[p] += r[p * 64 + o];
        #pragma unroll
        for (int p = 0; p < 16; p++) acc2[p] += r[(16 + p) * 64 + o];
    }
    __syncthreads();
    if (wv == 1) {
        float* r = red[0];
        r[32 * 64 + o] = accR;
        #pragma unroll
        for (int p = 0; p < 16; p++) r[p * 64 + o] = acc1[p];
        #pragma unroll
        for (int p = 0; p < 16; p++) r[(16 + p) * 64 + o] = acc2[p];
    }
    __syncthreads();
    if (wv == 0) {
        const float* r = red[0];
        accR += r[32 * 64 + o];
        #pragma unroll
        for (int p = 0; p < 16; p++) acc1[p] += r[p * 64 + o];
        #pragma unroll
        for (int p = 0; p < 16; p++) acc2[p] += r[(16 + p) * 64 + o];

        float* ac = accum_out + (size_t)b * ACC_PER_B;
        atomicAdd(ac + 32 * 64 + o, accR);
        #pragma unroll
        for (int p = 0; p < 16; p++) atomicAdd(ac + p * 64 + o, acc1[p]);
        #pragma unroll
        for (int p = 0; p < 16; p++) atomicAdd(ac + (16 + p) * 64 + o, acc2[p]);
    }
}

__global__ __launch_bounds__(64) void stats_final(
    const float* __restrict__ accum,   // [B][33][64] summed
    const float* __restrict__ beta_v,  // [64]
    const float* __restrict__ beta_a,  // [64]
    float* __restrict__ out,
    float inv_temp)
{
    const int b = blockIdx.x;
    const int o = threadIdx.x;  // 64 threads = 1 wave
    const float* ac = accum + (size_t)b * ACC_PER_B;

    float rps = ac[32 * 64 + o];
    float rinv = 1.0f / rps;
    float m[16];
    float logsum = 0.f;
    #pragma unroll
    for (int p = 0; p < 16; p++) {
        float mm = ac[p * 64 + o] * rinv;
        float vv = fmaxf(ac[(16 + p) * 64 + o] * rinv - mm * mm, 0.f);
        m[p] = mm;
        logsum += __logf(sqrtf(vv) + EPSF);
    }
    float cost = rps * (16.0f * beta_v[o] + logsum);

    float cm = cost;
    #pragma unroll
    for (int s = 32; s > 0; s >>= 1) cm += __shfl_xor(cm, s, 64);
    cm *= (1.0f / 64.0f);
    float dd = cost - cm;
    float cs = dd * dd;
    #pragma unroll
    for (int s = 32; s > 0; s >>= 1) cs += __shfl_xor(cs, s, 64);
    cs = sqrtf(cs * (1.0f / 64.0f));

    float x = inv_temp * (beta_a[o] + (cm - cost) / (cs + EPSF));
    float oa = 1.0f / (1.0f + __expf(-x));

    float* op = out + ((size_t)b * 64 + o) * 16;
    #pragma unroll
    for (int p = 0; p < 16; p++) op[p] = m[p];
    out[(size_t)NB * NO * NP + (size_t)b * 64 + o] = oa;
}

extern "C" void kernel_launch(void* const* d_in, const int* in_sizes, int n_in,
                              void* d_out, int out_size, void* d_ws, size_t ws_size,
                              hipStream_t stream) {
    const float* pose   = (const float*)d_in[0];  // (32,8,8,32,4,4)
    const float* act    = (const float*)d_in[1];  // (32,8,8,32)
    const float* wmat   = (const float*)d_in[2];  // (32,64,4,4)
    const float* beta_v = (const float*)d_in[3];  // (1,64)
    const float* beta_a = (const float*)d_in[4];  // (1,64)
    float* out = (float*)d_out;
    float* ws = (float*)d_ws;

    float* a0 = ws;
    float* a1 = ws + (size_t)ACC_TOTAL;
    float* a2 = ws + 2 * (size_t)ACC_TOTAL;

    // zero the three atomic accumulators (ws is poisoned before every call)
    hipMemsetAsync(ws, 0, 3 * (size_t)ACC_TOTAL * sizeof(float), stream);

    dim3 grid(64, NB);
    accum_kernel<true ><<<grid, 256, 0, stream>>>(pose, act, wmat, beta_v, beta_a,
                                                  nullptr, a0, 0.0f);
    accum_kernel<false><<<grid, 256, 0, stream>>>(pose, act, wmat, beta_v, beta_a,
                                                  a0, a1, 1.0f);
    accum_kernel<false><<<grid, 256, 0, stream>>>(pose, act, wmat, beta_v, beta_a,
                                                  a1, a2, 2.0f);
    stats_final<<<NB, 64, 0, stream>>>(a2, beta_v, beta_a, out, 3.0f);
}